// Round 1
// baseline (619.079 us; speedup 1.0000x reference)
//
#include <hip/hip_runtime.h>

// Problem constants (from reference): x (4,64,112,112) fp32, K=7, STRIDE=1,
// PAD=3, DIL=1, reflect padding. H_out=W_out=112.
// out (N, C, 49, 12544) fp32: out[n,c,kh*7+kw, h*112+w] =
//   x[n,c,h,w] - x[n,c, refl(h+kh-3), refl(w+kw-3)]
// refl(t) = -t if t<0 ; 2*(D-1)-t if t>D-1  (jnp reflect, edge not repeated)

#define NC_   256      // N*C
#define H_    112
#define W_    112
#define K_    7
#define PADV  3
#define HW    12544    // H*W
#define W4_   28       // W/4
#define K2_   49

typedef float vf4 __attribute__((ext_vector_type(4)));

__global__ __launch_bounds__(256) void san_sub_kernel(const float* __restrict__ x,
                                                      float* __restrict__ out) {
    int tid  = blockIdx.x * blockDim.x + threadIdx.x;   // exact grid, no bounds check
    int w4   = tid % W4_;
    int rest = tid / W4_;
    int h    = rest % H_;
    int nc   = rest / H_;

    int wbase = w4 * 4;
    const float* xc = x + nc * HW;

    vf4 center = *reinterpret_cast<const vf4*>(xc + h * W_ + wbase);

    float* outp = out + (size_t)nc * (K2_ * HW) + h * W_ + wbase;

    #pragma unroll
    for (int kh = 0; kh < K_; ++kh) {
        int r = h + kh - PADV;
        r = (r < 0) ? -r : r;
        r = (r > H_ - 1) ? (2 * (H_ - 1) - r) : r;
        const float* xrow = xc + r * W_;

        // 10-float register window covering columns [wbase-3, wbase+6],
        // branch-free reflect clamp (wave-uniform control flow).
        float win[10];
        #pragma unroll
        for (int t = 0; t < 10; ++t) {
            int col = wbase - PADV + t;
            col = (col < 0) ? -col : col;
            col = (col > W_ - 1) ? (2 * (W_ - 1) - col) : col;
            win[t] = xrow[col];
        }

        #pragma unroll
        for (int kw = 0; kw < K_; ++kw) {
            vf4 o;
            o.x = center.x - win[kw + 0];
            o.y = center.y - win[kw + 1];
            o.z = center.z - win[kw + 2];
            o.w = center.w - win[kw + 3];
            __builtin_nontemporal_store(
                o, reinterpret_cast<vf4*>(outp + (size_t)(kh * K_ + kw) * HW));
        }
    }
}

extern "C" void kernel_launch(void* const* d_in, const int* in_sizes, int n_in,
                              void* d_out, int out_size, void* d_ws, size_t ws_size,
                              hipStream_t stream) {
    const float* x = (const float*)d_in[0];
    float* out = (float*)d_out;
    // total threads = NC * H * W4 = 256*112*28 = 802816 = 3136 blocks * 256
    dim3 grid(NC_ * H_ * W4_ / 256);
    dim3 block(256);
    san_sub_kernel<<<grid, block, 0, stream>>>(x, out);
}